// Round 2
// baseline (419.087 us; speedup 1.0000x reference)
//
#include <hip/hip_runtime.h>
#include <hip/hip_bf16.h>

#define DD 128   // feature dim
#define HH 16    // hidden dim

// ---------------------------------------------------------------------------
// K0: collapse layer-2 + classifier into 16-dim vectors.
//   wsu[0..15]  = u_l1[j] = sum_d w2_l[j,d] * wc[d]        (agg path, article1 half)
//   wsu[16..31] = u_l2[j] = sum_d w2_l[j,d] * wc[128+d]    (agg path, article2 half)
//   wsu[32..47] = u_r1[j] = sum_d w2_r[j,d] * wc[d]
//   wsu[48..63] = u_r2[j] = sum_d w2_r[j,d] * wc[128+d]
//   wsu[64] = b2.wc[:128] + bc ;  wsu[65] = b2.wc[128:]
// ---------------------------------------------------------------------------
__global__ void k_prep(const float* __restrict__ w2l, const float* __restrict__ w2r,
                       const float* __restrict__ b2v, const float* __restrict__ wc,
                       const float* __restrict__ bc, float* __restrict__ wsu) {
    int t = threadIdx.x;
    if (t < 64) {
        int k = t >> 4, j = t & 15;
        const float* W = (k < 2) ? w2l : w2r;
        int off = (k & 1) * DD;
        float s = 0.f;
        for (int d = 0; d < DD; ++d) s += W[j * DD + d] * wc[off + d];
        wsu[k * 16 + j] = s;
    } else if (t == 64) {
        float s = bc[0];
        for (int d = 0; d < DD; ++d) s += b2v[d] * wc[d];
        wsu[64] = s;
    } else if (t == 65) {
        float s = 0.f;
        for (int d = 0; d < DD; ++d) s += b2v[d] * wc[DD + d];
        wsu[65] = s;
    }
}

// ---------------------------------------------------------------------------
// K1: y1 = x @ w1_l, z1 = x @ w1_r   (x: [N,128] f32 -> y1,z1: [N,16] f32)
// 16 rows per block of 256 threads; 16 lanes per row (lane j = output col).
// ---------------------------------------------------------------------------
__global__ __launch_bounds__(256) void k_xform(const float* __restrict__ x,
                                               const float* __restrict__ w1l,
                                               const float* __restrict__ w1r,
                                               float* __restrict__ y1,
                                               float* __restrict__ z1, int N) {
    __shared__ float wl[DD * HH];     // 2048 f32
    __shared__ float wr[DD * HH];
    __shared__ float xt[16 * 132];    // row stride 132 (132%4==0 -> float4-writable)

    const int tid  = threadIdx.x;
    const int row0 = blockIdx.x * 16;

    // weights: 2048 f32 = 512 float4 each -> 2 per thread
    {
        const float4* a = (const float4*)w1l;
        const float4* b = (const float4*)w1r;
        ((float4*)wl)[tid]       = a[tid];
        ((float4*)wl)[tid + 256] = a[tid + 256];
        ((float4*)wr)[tid]       = b[tid];
        ((float4*)wr)[tid + 256] = b[tid + 256];
    }
    // x tile: 16 rows x 128 f32 = 512 float4 -> 2 per thread (padded stride 33 f4)
    {
        for (int k = 0; k < 2; ++k) {
            int idx = tid + k * 256;
            int r = idx >> 5, seg = idx & 31;
            if (row0 + r < N) {
                float4 v = ((const float4*)(x + (size_t)(row0 + r) * DD))[seg];
                ((float4*)xt)[r * 33 + seg] = v;
            }
        }
    }
    __syncthreads();

    const int r = tid >> 4, j = tid & 15;
    const int row = row0 + r;
    if (row >= N) return;
    float accy = 0.f, accz = 0.f;
#pragma unroll 8
    for (int d = 0; d < DD; ++d) {
        float xv = xt[r * 132 + d];
        accy += xv * wl[d * HH + j];
        accz += xv * wr[d * HH + j];
    }
    y1[(size_t)row * HH + j] = accy;
    z1[(size_t)row * HH + j] = accz;
}

// ---------------------------------------------------------------------------
// K2/K5: edge scatter-add. 16 lanes per edge; lane j handles feature j.
// Optionally accumulates in-degree (first pass only).
// ---------------------------------------------------------------------------
__global__ __launch_bounds__(256) void k_edge(const int* __restrict__ src,
                                              const int* __restrict__ dst,
                                              const float* __restrict__ feat,
                                              float* __restrict__ agg,
                                              float* __restrict__ deg, int E) {
    int t = blockIdx.x * 256 + threadIdx.x;
    int e = t >> 4, j = t & 15;
    if (e >= E) return;
    int s = src[e], d = dst[e];
    atomicAdd(&agg[(size_t)d * HH + j], feat[(size_t)s * HH + j]);
    if (deg != nullptr && j == 0) atomicAdd(&deg[d], 1.0f);
}

// K3: deg -> 1/max(deg,1)  (in place)
__global__ void k_invdeg(float* __restrict__ deg, int N) {
    int i = blockIdx.x * blockDim.x + threadIdx.x;
    if (i < N) deg[i] = 1.0f / fmaxf(deg[i], 1.0f);
}

// K4: h = relu(agg1*invdeg + b1 + z1)
__global__ void k_hidden(const float* __restrict__ agg1, const float* __restrict__ z1,
                         const float* __restrict__ invdeg, const float* __restrict__ b1,
                         float* __restrict__ h, int total) {
    int i = blockIdx.x * blockDim.x + threadIdx.x;
    if (i >= total) return;
    int n = i >> 4, j = i & 15;
    float v = agg1[i] * invdeg[n] + b1[j] + z1[i];
    h[i] = fmaxf(v, 0.f);
}

// ---------------------------------------------------------------------------
// K6: per-pair logits + BCE partial sums. 16 lanes per pair.
// ---------------------------------------------------------------------------
__global__ __launch_bounds__(256) void k_pair(const float* __restrict__ h,
                                              const float* __restrict__ aggh,
                                              const float* __restrict__ invdeg,
                                              const int* __restrict__ a1,
                                              const int* __restrict__ a2,
                                              const int* __restrict__ labels,
                                              const float* __restrict__ wsu,
                                              float* __restrict__ out_logits,
                                              float* __restrict__ lacc, int B) {
    __shared__ float lred[16];
    int t = blockIdx.x * 256 + threadIdx.x;
    int p = t >> 4, j = t & 15;
    int g = threadIdx.x >> 4;                 // group within block

    float myloss = 0.f;
    if (p < B) {
        int i1 = a1[p], i2 = a2[p];
        float ul1 = wsu[j], ul2 = wsu[16 + j], ur1 = wsu[32 + j], ur2 = wsu[48 + j];
        float v = aggh[(size_t)i1 * HH + j] * invdeg[i1] * ul1
                + h[(size_t)i1 * HH + j] * ur1
                + aggh[(size_t)i2 * HH + j] * invdeg[i2] * ul2
                + h[(size_t)i2 * HH + j] * ur2;
#pragma unroll
        for (int off = 8; off; off >>= 1) v += __shfl_xor(v, off, 16);
        if (j == 0) {
            float l = v + wsu[64] + wsu[65];
            out_logits[p] = l;
            float y = (float)labels[p];
            myloss = fmaxf(l, 0.f) - l * y + log1pf(expf(-fabsf(l)));
        }
    }
    if (j == 0) lred[g] = myloss;
    __syncthreads();
    if (threadIdx.x == 0) {
        float s = 0.f;
#pragma unroll
        for (int k = 0; k < 16; ++k) s += lred[k];
        atomicAdd(lacc, s);
    }
}

// K7: out[0] = loss mean
__global__ void k_final(const float* __restrict__ lacc, float* __restrict__ out, float invB) {
    out[0] = lacc[0] * invB;
}

// ---------------------------------------------------------------------------
extern "C" void kernel_launch(void* const* d_in, const int* in_sizes, int n_in,
                              void* d_out, int out_size, void* d_ws, size_t ws_size,
                              hipStream_t stream) {
    const float* x    = (const float*)d_in[0];
    const float* w1l  = (const float*)d_in[1];
    const float* b1   = (const float*)d_in[2];
    const float* w1r  = (const float*)d_in[3];
    const float* w2l  = (const float*)d_in[4];
    const float* b2v  = (const float*)d_in[5];
    const float* w2r  = (const float*)d_in[6];
    const float* wc   = (const float*)d_in[7];
    const float* bc   = (const float*)d_in[8];
    const int*   ei   = (const int*)d_in[9];
    const int*   a1   = (const int*)d_in[10];
    const int*   a2   = (const int*)d_in[11];
    const int*   lab  = (const int*)d_in[12];

    const int N = in_sizes[0] / DD;
    const int E = in_sizes[9] / 2;
    const int B = in_sizes[10];

    const int* src = ei;
    const int* dst = ei + E;

    // workspace layout (bytes)
    char* ws = (char*)d_ws;
    const size_t NH4 = (size_t)N * HH * 4;
    float* wsu  = (float*)ws;                      // 512 B
    float* y1   = (float*)(ws + 512);
    float* z1   = (float*)(ws + 512 + NH4);
    float* h    = (float*)(ws + 512 + 2 * NH4);
    float* agg1 = (float*)(ws + 512 + 3 * NH4);    // zeroed region starts here
    float* aggh = (float*)(ws + 512 + 4 * NH4);
    float* deg  = (float*)(ws + 512 + 5 * NH4);
    float* lacc = (float*)(ws + 512 + 5 * NH4 + (size_t)N * 4);
    const size_t zero_bytes = 2 * NH4 + (size_t)N * 4 + 4;

    float* out = (float*)d_out;           // out[0] = loss, out[1..B] = logits

    hipMemsetAsync((void*)agg1, 0, zero_bytes, stream);

    k_prep<<<1, 128, 0, stream>>>(w2l, w2r, b2v, wc, bc, wsu);

    k_xform<<<(N + 15) / 16, 256, 0, stream>>>(x, w1l, w1r, y1, z1, N);

    {
        int blocks = (int)(((size_t)E * 16 + 255) / 256);
        k_edge<<<blocks, 256, 0, stream>>>(src, dst, y1, agg1, deg, E);
    }

    k_invdeg<<<(N + 255) / 256, 256, 0, stream>>>(deg, N);

    k_hidden<<<(N * HH + 255) / 256, 256, 0, stream>>>(agg1, z1, deg, b1, h, N * HH);

    {
        int blocks = (int)(((size_t)E * 16 + 255) / 256);
        k_edge<<<blocks, 256, 0, stream>>>(src, dst, h, aggh, nullptr, E);
    }

    k_pair<<<(B * 16 + 255) / 256, 256, 0, stream>>>(h, aggh, deg, a1, a2, lab, wsu,
                                                     out + 1, lacc, B);

    k_final<<<1, 1, 0, stream>>>(lacc, out, 1.0f / (float)B);
}

// Round 3
// 419.012 us; speedup vs baseline: 1.0002x; 1.0002x over previous
//
#include <hip/hip_runtime.h>
#include <hip/hip_bf16.h>

#define DD 128   // feature dim
#define HH 16    // hidden dim

// ---------------------------------------------------------------------------
// K0: collapse layer-2 + classifier into 16-dim vectors.
//   wsu[0..15]  = u_l1[j] = sum_d w2_l[j,d] * wc[d]
//   wsu[16..31] = u_l2[j] = sum_d w2_l[j,d] * wc[128+d]
//   wsu[32..47] = u_r1[j] = sum_d w2_r[j,d] * wc[d]
//   wsu[48..63] = u_r2[j] = sum_d w2_r[j,d] * wc[128+d]
//   wsu[64] = b2.wc[:128] + bc ;  wsu[65] = b2.wc[128:]
// ---------------------------------------------------------------------------
__global__ void k_prep(const float* __restrict__ w2l, const float* __restrict__ w2r,
                       const float* __restrict__ b2v, const float* __restrict__ wc,
                       const float* __restrict__ bc, float* __restrict__ wsu) {
    int t = threadIdx.x;
    if (t < 64) {
        int k = t >> 4, j = t & 15;
        const float* W = (k < 2) ? w2l : w2r;
        int off = (k & 1) * DD;
        float s = 0.f;
        for (int d = 0; d < DD; ++d) s += W[j * DD + d] * wc[off + d];
        wsu[k * 16 + j] = s;
    } else if (t == 64) {
        float s = bc[0];
        for (int d = 0; d < DD; ++d) s += b2v[d] * wc[d];
        wsu[64] = s;
    } else if (t == 65) {
        float s = 0.f;
        for (int d = 0; d < DD; ++d) s += b2v[d] * wc[DD + d];
        wsu[65] = s;
    }
}

// ---------------------------------------------------------------------------
// K1: y1 = x @ w1_l, z1 = x @ w1_r   (x: [N,128] f32 -> y1,z1: [N,16] f32)
// ---------------------------------------------------------------------------
__global__ __launch_bounds__(256) void k_xform(const float* __restrict__ x,
                                               const float* __restrict__ w1l,
                                               const float* __restrict__ w1r,
                                               float* __restrict__ y1,
                                               float* __restrict__ z1, int N) {
    __shared__ float wl[DD * HH];
    __shared__ float wr[DD * HH];
    __shared__ float xt[16 * 132];    // row stride 132 floats (33 float4)

    const int tid  = threadIdx.x;
    const int row0 = blockIdx.x * 16;

    {
        const float4* a = (const float4*)w1l;
        const float4* b = (const float4*)w1r;
        ((float4*)wl)[tid]       = a[tid];
        ((float4*)wl)[tid + 256] = a[tid + 256];
        ((float4*)wr)[tid]       = b[tid];
        ((float4*)wr)[tid + 256] = b[tid + 256];
    }
    {
        for (int k = 0; k < 2; ++k) {
            int idx = tid + k * 256;
            int r = idx >> 5, seg = idx & 31;
            if (row0 + r < N) {
                float4 v = ((const float4*)(x + (size_t)(row0 + r) * DD))[seg];
                ((float4*)xt)[r * 33 + seg] = v;
            }
        }
    }
    __syncthreads();

    const int r = tid >> 4, j = tid & 15;
    const int row = row0 + r;
    if (row >= N) return;
    float accy = 0.f, accz = 0.f;
#pragma unroll 8
    for (int d = 0; d < DD; ++d) {
        float xv = xt[r * 132 + d];
        accy += xv * wl[d * HH + j];
        accz += xv * wr[d * HH + j];
    }
    y1[(size_t)row * HH + j] = accy;
    z1[(size_t)row * HH + j] = accz;
}

// ---------------------------------------------------------------------------
// K2: in-degree histogram (int atomics, 4 edges/thread via int4)
// ---------------------------------------------------------------------------
__global__ __launch_bounds__(256) void k_count(const int* __restrict__ dst,
                                               int* __restrict__ cnt, int E4) {
    int i = blockIdx.x * 256 + threadIdx.x;
    if (i >= E4) return;
    int4 d = ((const int4*)dst)[i];
    atomicAdd(&cnt[d.x], 1);
    atomicAdd(&cnt[d.y], 1);
    atomicAdd(&cnt[d.z], 1);
    atomicAdd(&cnt[d.w], 1);
}

// ---------------------------------------------------------------------------
// K3: allocate CSR slices — block-level scan + one global atomic per block.
// Also emits invdeg = 1/max(cnt,1). CSR slice order across blocks is
// arbitrary (atomic cursor), which is fine: slices are disjoint.
// ---------------------------------------------------------------------------
__global__ __launch_bounds__(256) void k_alloc(const int* __restrict__ cnt,
                                               int* __restrict__ startv,
                                               int* __restrict__ pos,
                                               float* __restrict__ invdeg,
                                               int* __restrict__ cursor, int N) {
    __shared__ int wsum[4];
    __shared__ int wbase[4];
    int i = blockIdx.x * 256 + threadIdx.x;
    int wid = threadIdx.x >> 6, lane = threadIdx.x & 63;
    int c = (i < N) ? cnt[i] : 0;
    int v = c;
#pragma unroll
    for (int off = 1; off < 64; off <<= 1) {
        int u = __shfl_up(v, off, 64);
        if (lane >= off) v += u;
    }
    if (lane == 63) wsum[wid] = v;
    __syncthreads();
    if (threadIdx.x == 0) {
        int s0 = wsum[0], s1 = wsum[1], s2 = wsum[2], s3 = wsum[3];
        int b = atomicAdd(cursor, s0 + s1 + s2 + s3);
        wbase[0] = b; wbase[1] = b + s0; wbase[2] = b + s0 + s1; wbase[3] = b + s0 + s1 + s2;
    }
    __syncthreads();
    if (i < N) {
        int st = wbase[wid] + v - c;   // exclusive scan position
        startv[i] = st;
        pos[i] = st;
        invdeg[i] = 1.0f / fmaxf((float)c, 1.0f);
    }
}

// ---------------------------------------------------------------------------
// K4: scatter src ids into CSR slots (int atomics on per-node cursors)
// ---------------------------------------------------------------------------
__global__ __launch_bounds__(256) void k_scatter(const int* __restrict__ src,
                                                 const int* __restrict__ dst,
                                                 int* __restrict__ pos,
                                                 int* __restrict__ csr, int E4) {
    int i = blockIdx.x * 256 + threadIdx.x;
    if (i >= E4) return;
    int4 s = ((const int4*)src)[i];
    int4 d = ((const int4*)dst)[i];
    int p;
    p = atomicAdd(&pos[d.x], 1); csr[p] = s.x;
    p = atomicAdd(&pos[d.y], 1); csr[p] = s.y;
    p = atomicAdd(&pos[d.z], 1); csr[p] = s.z;
    p = atomicAdd(&pos[d.w], 1); csr[p] = s.w;
}

// ---------------------------------------------------------------------------
// K5: pull-based segment mean. 16 lanes per node, lane j = feature j.
// mode 0: out = relu(sum*invdeg + b1[j] + z1)   (layer-1 hidden, fuses k_hidden)
// mode 1: out = sum*invdeg                       (layer-2 agg, pre-scaled)
// ---------------------------------------------------------------------------
__global__ __launch_bounds__(256) void k_agg(const int* __restrict__ csr,
                                             const int* __restrict__ startv,
                                             const int* __restrict__ cnt,
                                             const float* __restrict__ feat,
                                             const float* __restrict__ invdeg,
                                             const float* __restrict__ z1,
                                             const float* __restrict__ b1,
                                             float* __restrict__ outv,
                                             int N, int mode) {
    int t = blockIdx.x * 256 + threadIdx.x;
    int node = t >> 4, j = t & 15;
    if (node >= N) return;
    int st = startv[node], c = cnt[node];
    const int* ids = csr + st;
    float acc0 = 0.f, acc1 = 0.f;
    int k = 0;
    for (; k + 2 <= c; k += 2) {          // 2-way to expose memory ILP
        int s0 = ids[k], s1 = ids[k + 1];
        acc0 += feat[(size_t)s0 * HH + j];
        acc1 += feat[(size_t)s1 * HH + j];
    }
    if (k < c) acc0 += feat[(size_t)ids[k] * HH + j];
    float acc = acc0 + acc1;
    float inv = invdeg[node];
    size_t o = (size_t)node * HH + j;
    if (mode == 0) {
        outv[o] = fmaxf(acc * inv + b1[j] + z1[o], 0.f);
    } else {
        outv[o] = acc * inv;
    }
}

// ---------------------------------------------------------------------------
// K6: per-pair logits + BCE partial sums. 16 lanes per pair.
// aggs is pre-scaled by invdeg, so no invdeg gathers here.
// ---------------------------------------------------------------------------
__global__ __launch_bounds__(256) void k_pair(const float* __restrict__ h,
                                              const float* __restrict__ aggs,
                                              const int* __restrict__ a1,
                                              const int* __restrict__ a2,
                                              const int* __restrict__ labels,
                                              const float* __restrict__ wsu,
                                              float* __restrict__ out_logits,
                                              float* __restrict__ lacc, int B) {
    __shared__ float lred[16];
    int t = blockIdx.x * 256 + threadIdx.x;
    int p = t >> 4, j = t & 15;
    int g = threadIdx.x >> 4;

    float myloss = 0.f;
    if (p < B) {
        int i1 = a1[p], i2 = a2[p];
        float v = aggs[(size_t)i1 * HH + j] * wsu[j]
                + h[(size_t)i1 * HH + j] * wsu[32 + j]
                + aggs[(size_t)i2 * HH + j] * wsu[16 + j]
                + h[(size_t)i2 * HH + j] * wsu[48 + j];
#pragma unroll
        for (int off = 8; off; off >>= 1) v += __shfl_xor(v, off, 16);
        if (j == 0) {
            float l = v + wsu[64] + wsu[65];
            out_logits[p] = l;
            float y = (float)labels[p];
            myloss = fmaxf(l, 0.f) - l * y + log1pf(expf(-fabsf(l)));
        }
    }
    if (j == 0) lred[g] = myloss;
    __syncthreads();
    if (threadIdx.x == 0) {
        float s = 0.f;
#pragma unroll
        for (int k = 0; k < 16; ++k) s += lred[k];
        atomicAdd(lacc, s);
    }
}

// K7: out[0] = loss mean
__global__ void k_final(const float* __restrict__ lacc, float* __restrict__ out, float invB) {
    out[0] = lacc[0] * invB;
}

// ---------------------------------------------------------------------------
extern "C" void kernel_launch(void* const* d_in, const int* in_sizes, int n_in,
                              void* d_out, int out_size, void* d_ws, size_t ws_size,
                              hipStream_t stream) {
    const float* x    = (const float*)d_in[0];
    const float* w1l  = (const float*)d_in[1];
    const float* b1   = (const float*)d_in[2];
    const float* w1r  = (const float*)d_in[3];
    const float* w2l  = (const float*)d_in[4];
    const float* b2v  = (const float*)d_in[5];
    const float* w2r  = (const float*)d_in[6];
    const float* wc   = (const float*)d_in[7];
    const float* bc   = (const float*)d_in[8];
    const int*   ei   = (const int*)d_in[9];
    const int*   a1   = (const int*)d_in[10];
    const int*   a2   = (const int*)d_in[11];
    const int*   lab  = (const int*)d_in[12];

    const int N = in_sizes[0] / DD;
    const int E = in_sizes[9] / 2;
    const int B = in_sizes[10];

    const int* src = ei;
    const int* dst = ei + E;

    // workspace layout
    char* ws = (char*)d_ws;
    const size_t NH4 = (size_t)N * HH * 4;   // bytes of one [N,16] f32 buffer
    float* wsu    = (float*)ws;                           // 512 B
    float* y1     = (float*)(ws + 512);                   // [N,16] (reused as aggs)
    float* z1     = (float*)(ws + 512 + NH4);
    float* h      = (float*)(ws + 512 + 2 * NH4);
    int*   csr    = (int*)  (ws + 512 + 3 * NH4);         // [E]
    char*  p4     = ws + 512 + 3 * NH4 + (size_t)E * 4;
    int*   startv = (int*)p4;                             // [N]
    int*   pos    = (int*)(p4 + (size_t)N * 4);           // [N]
    float* invdeg = (float*)(p4 + 2 * (size_t)N * 4);     // [N]
    int*   cnt    = (int*)(p4 + 3 * (size_t)N * 4);       // [N]  -- zeroed
    int*   cursor = (int*)(p4 + 4 * (size_t)N * 4);       // [1]  -- zeroed
    float* lacc   = (float*)(p4 + 4 * (size_t)N * 4 + 4); // [1]  -- zeroed

    float* aggs = y1;   // layer-2 scaled aggregation reuses y1's buffer
    float* out  = (float*)d_out;   // out[0] = loss, out[1..B] = logits

    hipMemsetAsync((void*)cnt, 0, (size_t)N * 4 + 8, stream);

    k_prep<<<1, 128, 0, stream>>>(w2l, w2r, b2v, wc, bc, wsu);

    const int E4 = E / 4;  // E is a multiple of 4
    k_count<<<(E4 + 255) / 256, 256, 0, stream>>>(dst, cnt, E4);

    k_alloc<<<(N + 255) / 256, 256, 0, stream>>>(cnt, startv, pos, invdeg, cursor, N);

    k_scatter<<<(E4 + 255) / 256, 256, 0, stream>>>(src, dst, pos, csr, E4);

    k_xform<<<(N + 15) / 16, 256, 0, stream>>>(x, w1l, w1r, y1, z1, N);

    // layer 1: h = relu(mean(y1[src]) + b1 + z1)
    k_agg<<<((N * 16) + 255) / 256, 256, 0, stream>>>(csr, startv, cnt, y1, invdeg,
                                                      z1, b1, h, N, 0);
    // layer 2: aggs = mean(h[src])   (overwrites y1 — y1 is dead now)
    k_agg<<<((N * 16) + 255) / 256, 256, 0, stream>>>(csr, startv, cnt, h, invdeg,
                                                      nullptr, nullptr, aggs, N, 1);

    k_pair<<<(B * 16 + 255) / 256, 256, 0, stream>>>(h, aggs, a1, a2, lab, wsu,
                                                     out + 1, lacc, B);

    k_final<<<1, 1, 0, stream>>>(lacc, out, 1.0f / (float)B);
}